// Round 4
// baseline (150.105 us; speedup 1.0000x reference)
//
#include <hip/hip_runtime.h>
#include <math.h>

#define NB 512
#define NS 64
#define ND 2048
#define NP 1024  // ND/2

// ---------------- threefry2x32 (exact jax semantics, key=(0,42)) -------------
__device__ __forceinline__ unsigned rotl32(unsigned x, int d) {
    return (x << d) | (x >> (32 - d));
}

__device__ __forceinline__ void threefry2x32(unsigned k0, unsigned k1,
                                             unsigned& x0, unsigned& x1) {
    const unsigned ks0 = k0, ks1 = k1, ks2 = k0 ^ k1 ^ 0x1BD11BDAu;
    const int r0[4] = {13, 15, 26, 6};
    const int r1[4] = {17, 29, 16, 24};
    x0 += ks0; x1 += ks1;
#pragma unroll
    for (int i = 0; i < 4; ++i) { x0 += x1; x1 = rotl32(x1, r0[i]); x1 ^= x0; }
    x0 += ks1; x1 += ks2 + 1u;
#pragma unroll
    for (int i = 0; i < 4; ++i) { x0 += x1; x1 = rotl32(x1, r1[i]); x1 ^= x0; }
    x0 += ks2; x1 += ks0 + 2u;
#pragma unroll
    for (int i = 0; i < 4; ++i) { x0 += x1; x1 = rotl32(x1, r0[i]); x1 ^= x0; }
    x0 += ks0; x1 += ks1 + 3u;
#pragma unroll
    for (int i = 0; i < 4; ++i) { x0 += x1; x1 = rotl32(x1, r1[i]); x1 ^= x0; }
    x0 += ks1; x1 += ks2 + 4u;
#pragma unroll
    for (int i = 0; i < 4; ++i) { x0 += x1; x1 = rotl32(x1, r0[i]); x1 ^= x0; }
    x0 += ks2; x1 += ks0 + 5u;
}

// ---------------- K1: fused norms+softmax+M0/M1+Qt, one block per s-row ------
__global__ void __launch_bounds__(1024)
k_prepMQ(const float* __restrict__ amp, const float* __restrict__ ph,
         const float* __restrict__ G, const float* __restrict__ E,
         float* __restrict__ M0, float* __restrict__ M1, float* __restrict__ Qt) {
    __shared__ float norm2[NS];
    __shared__ float invn[NS];
    __shared__ float Wrow[NS];
    __shared__ float Gl[NS * 4];
    const int s = blockIdx.x;
    const int tid = threadIdx.x;

    // norms: 16 threads per amp-row (redundant per block; L2-resident, ~cheap)
    {
        int row = tid >> 4, sub = tid & 15;
        const float* arow = amp + row * ND;
        float acc = 0.f;
        for (int d = sub; d < ND; d += 16) { float v = arow[d]; acc += v * v; }
        for (int off = 8; off; off >>= 1) acc += __shfl_down(acc, off, 16);
        if (sub == 0) norm2[row] = acc;
    }
    if (tid < NS * 4) Gl[tid] = G[tid];
    __syncthreads();
    if (tid < NS) {  // wave 0: inv-norms + softmax of this block's E row
        invn[tid] = 1.0f / sqrtf(norm2[tid]);
        float e = E[s * NS + tid];
        float m = e;
        for (int off = 32; off; off >>= 1) m = fmaxf(m, __shfl_down(m, off));
        m = __shfl(m, 0);
        float ex = expf(e - m);
        float sum = ex;
        for (int off = 32; off; off >>= 1) sum += __shfl_down(sum, off);
        sum = __shfl(sum, 0);
        Wrow[tid] = ex / sum;
    }
    __syncthreads();

    // main: thread = pair p; M0/M1[s, 2p..2p+1] and Qt[., s]
    const int p = tid;  // 0..1023
    const float2* a2 = (const float2*)amp;
    const float2* p2 = (const float2*)ph;
    float a0 = 0.f, a1 = 0.f, b0 = 0.f, b1 = 0.f;
#pragma unroll 4
    for (int t = 0; t < NS; ++t) {
        float2 av = a2[t * NP + p];
        float2 pv = p2[t * NP + p];
        float w = Wrow[t], in = invn[t];
        float ra0 = av.x * in * (__cosf(pv.x) + __sinf(pv.x));
        float ra1 = av.y * in * (__cosf(pv.y) + __sinf(pv.y));
        float wr0 = w * ra0, wr1 = w * ra1;
        a0 += wr0 * Gl[4 * t + 0];
        b0 += wr0 * Gl[4 * t + 2];
        a1 += wr1 * Gl[4 * t + 1];
        b1 += wr1 * Gl[4 * t + 3];
    }
    float2 m0v = {a0, a1}, m1v = {b0, b1};
    ((float2*)(M0 + s * ND))[p] = m0v;
    ((float2*)(M1 + s * ND))[p] = m1v;
    Qt[(3 * p + 0) * NS + s] = a0 * a0 + a1 * a1;
    Qt[(3 * p + 1) * NS + s] = a0 * b0 + a1 * b1;
    Qt[(3 * p + 2) * NS + s] = b0 * b0 + b1 * b1;
}

// ---------------- K2: split-K logits GEMM: part[b][ks][s] --------------------
__global__ void k_logits(const float* __restrict__ x, const float* __restrict__ Qt,
                         float* __restrict__ part, int chunk, int nsplit) {
    int bt = blockIdx.x;   // 0..31 (16 b-rows each)
    int ks = blockIdx.y;   // 0..nsplit-1
    int w = threadIdx.x >> 6, lane = threadIdx.x & 63;
    int b0 = bt * 16 + w * 4;
    const float2* xp = (const float2*)x;
    float acc0 = 0.f, acc1 = 0.f, acc2 = 0.f, acc3 = 0.f;
    int p0 = ks * chunk;
#pragma unroll 4
    for (int p = p0; p < p0 + chunk; ++p) {
        float q0 = Qt[(3 * p + 0) * NS + lane];
        float q1 = Qt[(3 * p + 1) * NS + lane];
        float q2 = Qt[(3 * p + 2) * NS + lane];
        float2 v0 = xp[(b0 + 0) * NP + p];
        float2 v1 = xp[(b0 + 1) * NP + p];
        float2 v2 = xp[(b0 + 2) * NP + p];
        float2 v3 = xp[(b0 + 3) * NP + p];
        acc0 += v0.x * v0.x * q0 + 2.f * v0.x * v0.y * q1 + v0.y * v0.y * q2;
        acc1 += v1.x * v1.x * q0 + 2.f * v1.x * v1.y * q1 + v1.y * v1.y * q2;
        acc2 += v2.x * v2.x * q0 + 2.f * v2.x * v2.y * q1 + v2.y * v2.y * q2;
        acc3 += v3.x * v3.x * q0 + 2.f * v3.x * v3.y * q1 + v3.y * v3.y * q2;
    }
    part[((b0 + 0) * nsplit + ks) * NS + lane] = acc0;
    part[((b0 + 1) * nsplit + ks) * NS + lane] = acc1;
    part[((b0 + 2) * nsplit + ks) * NS + lane] = acc2;
    part[((b0 + 3) * nsplit + ks) * NS + lane] = acc3;
}

// ---------------- K3: fused gumbel-max collapse + gather/linear-map ----------
__global__ void k_collapse_out(const float* __restrict__ part,
                               const float* __restrict__ x,
                               const float* __restrict__ M0,
                               const float* __restrict__ M1,
                               float* __restrict__ out, int nsplit) {
    __shared__ int o_sh;
    const int b = blockIdx.x;
    const int tid = threadIdx.x;
    if (tid < 64) {  // wave 0: jax categorical via gumbel-max (partitionable threefry)
        float l = 0.f;
        const float* pb = part + b * nsplit * NS + tid;
        for (int k = 0; k < nsplit; ++k) l += pb[k * NS];
        unsigned n = (unsigned)(b * NS + tid);
        unsigned x0 = 0u, x1 = n;  // counter = (hi32(n), lo32(n)), n < 2^32
        threefry2x32(0u, 42u, x0, x1);
        unsigned bits = x0 ^ x1;
        float u = (float)(bits >> 9) * (1.0f / 8388608.0f);
        u = fmaxf(u, 1.17549435e-38f);
        float g = -logf(-logf(u));
        float best = l + g;
        int bi = tid;
        for (int off = 32; off; off >>= 1) {
            float ov = __shfl_down(best, off);
            int oi = __shfl_down(bi, off);
            if (ov > best || (ov == best && oi < bi)) { best = ov; bi = oi; }
        }
        if (tid == 0) o_sh = bi;
    }
    __syncthreads();
    const int o = o_sh;
    const float2* xp = (const float2*)x + b * NP;
    const float2* m0p = (const float2*)(M0 + o * ND);
    const float2* m1p = (const float2*)(M1 + o * ND);
    float2* op = (float2*)out + b * NP;
#pragma unroll
    for (int i = 0; i < 4; ++i) {
        int p = tid + i * 256;
        float2 xv = xp[p], m0 = m0p[p], m1 = m1p[p];
        float2 r;
        r.x = xv.x * m0.x + xv.y * m1.x;
        r.y = xv.x * m0.y + xv.y * m1.y;
        op[p] = r;
    }
}

extern "C" void kernel_launch(void* const* d_in, const int* in_sizes, int n_in,
                              void* d_out, int out_size, void* d_ws, size_t ws_size,
                              hipStream_t stream) {
    const float* x   = (const float*)d_in[0];  // [512,2048]
    const float* amp = (const float*)d_in[1];  // [64,2048]
    const float* ph  = (const float*)d_in[2];  // [64,2048]
    const float* G   = (const float*)d_in[3];  // [64,2,2]
    const float* E   = (const float*)d_in[4];  // [64,64]
    float* out = (float*)d_out;
    float* ws = (float*)d_ws;

    // ws layout (float offsets)
    float* M0   = ws;                  // 131072
    float* M1   = ws + 131072;         // 131072
    float* Qt   = ws + 262144;         // 3*1024*64 = 196608
    float* part = ws + 458752;         // nsplit*512*64

    int nsplit = 16;
    while (nsplit > 2 && (size_t)(458752 + nsplit * NB * NS) * 4 > ws_size) nsplit >>= 1;
    int chunk = NP / nsplit;

    k_prepMQ      <<<64, 1024, 0, stream>>>(amp, ph, G, E, M0, M1, Qt);
    k_logits      <<<dim3(32, nsplit), 256, 0, stream>>>(x, Qt, part, chunk, nsplit);
    k_collapse_out<<<512, 256, 0, stream>>>(part, x, M0, M1, out, nsplit);
}

// Round 5
// 143.455 us; speedup vs baseline: 1.0464x; 1.0464x over previous
//
#include <hip/hip_runtime.h>
#include <math.h>

#define NB 512
#define NS 64
#define ND 2048
#define NP 1024   // ND/2
#define NBLK 256  // grid size; must be <= #CUs so all blocks are co-resident

// ---------------- threefry2x32 (exact jax semantics, key=(0,42)) -------------
__device__ __forceinline__ unsigned rotl32(unsigned x, int d) {
    return (x << d) | (x >> (32 - d));
}

__device__ __forceinline__ void threefry2x32(unsigned k0, unsigned k1,
                                             unsigned& x0, unsigned& x1) {
    const unsigned ks0 = k0, ks1 = k1, ks2 = k0 ^ k1 ^ 0x1BD11BDAu;
    const int r0[4] = {13, 15, 26, 6};
    const int r1[4] = {17, 29, 16, 24};
    x0 += ks0; x1 += ks1;
#pragma unroll
    for (int i = 0; i < 4; ++i) { x0 += x1; x1 = rotl32(x1, r0[i]); x1 ^= x0; }
    x0 += ks1; x1 += ks2 + 1u;
#pragma unroll
    for (int i = 0; i < 4; ++i) { x0 += x1; x1 = rotl32(x1, r1[i]); x1 ^= x0; }
    x0 += ks2; x1 += ks0 + 2u;
#pragma unroll
    for (int i = 0; i < 4; ++i) { x0 += x1; x1 = rotl32(x1, r0[i]); x1 ^= x0; }
    x0 += ks0; x1 += ks1 + 3u;
#pragma unroll
    for (int i = 0; i < 4; ++i) { x0 += x1; x1 = rotl32(x1, r1[i]); x1 ^= x0; }
    x0 += ks1; x1 += ks2 + 4u;
#pragma unroll
    for (int i = 0; i < 4; ++i) { x0 += x1; x1 = rotl32(x1, r0[i]); x1 ^= x0; }
    x0 += ks2; x1 += ks0 + 5u;
}

// Device-scope grid barrier. Counter starts at S (uniform poison value read from
// a never-written sentinel word); each block adds 1; spin until S+NBLK.
// __threadfence() = agent-scope fence (L2 writeback / invalidate) -> phase data
// written by other blocks (other XCDs) is visible after the barrier (G16).
__device__ __forceinline__ void grid_barrier(int* cnt, int target) {
    __syncthreads();
    if (threadIdx.x == 0) {
        __threadfence();           // release: flush this XCD's writes
        atomicAdd(cnt, 1);
        while (atomicAdd(cnt, 0) != target) __builtin_amdgcn_s_sleep(1);
        __threadfence();           // acquire: drop stale L1/L2 lines
    }
    __syncthreads();
}

__global__ void __launch_bounds__(256)
k_all(const float* __restrict__ x, const float* __restrict__ amp,
      const float* __restrict__ ph, const float* __restrict__ G,
      const float* __restrict__ E, float* __restrict__ out,
      int* __restrict__ bar, float* __restrict__ invn, float* __restrict__ Wm,
      float* __restrict__ M0, float* __restrict__ M1, float* __restrict__ Qt) {
    __shared__ float2 xs[2 * NP];          // 16 KB: two x rows (as pairs)
    __shared__ float part[2][4][NS];       // 2 KB : split-K partial logits
    __shared__ float red[256];
    __shared__ float W_l[NS], in_l[NS], G_l[NS * 4];
    __shared__ int o_sh[2];

    const int blk = blockIdx.x;
    const int tid = threadIdx.x;
    const int S = *(volatile int*)&bar[0];  // sentinel: uniform initial ws value

    // ---------------- phase 0: norms (blocks 0-63) + softmax (64-127) --------
    if (blk < 64) {
        const float4* a4 = (const float4*)(amp + blk * ND);  // 512 float4s
        float4 v0 = a4[tid], v1 = a4[tid + 256];
        float acc = v0.x * v0.x + v0.y * v0.y + v0.z * v0.z + v0.w * v0.w +
                    v1.x * v1.x + v1.y * v1.y + v1.z * v1.z + v1.w * v1.w;
        for (int off = 32; off; off >>= 1) acc += __shfl_down(acc, off);
        if ((tid & 63) == 0) red[tid >> 6] = acc;
        __syncthreads();
        if (tid == 0) invn[blk] = 1.0f / sqrtf(red[0] + red[1] + red[2] + red[3]);
    } else if (blk < 128) {
        if (tid < NS) {
            int srow = blk - 64;
            float e = E[srow * NS + tid];
            float m = e;
            for (int off = 32; off; off >>= 1) m = fmaxf(m, __shfl_down(m, off));
            m = __shfl(m, 0);
            float ex = expf(e - m);
            float sum = ex;
            for (int off = 32; off; off >>= 1) sum += __shfl_down(sum, off);
            sum = __shfl(sum, 0);
            Wm[srow * NS + tid] = ex / sum;
        }
    }
    grid_barrier(&bar[1], S + NBLK);

    // ---------------- phase 1: M0/M1/Qt; 4 blocks per s-row ------------------
    {
        const int srow = blk >> 2;
        const int p = ((blk & 3) << 8) + tid;  // 0..1023
        if (tid < NS) {
            W_l[tid] = Wm[srow * NS + tid];
            in_l[tid] = invn[tid];
        }
        G_l[tid] = G[tid];  // 256 = NS*4
        __syncthreads();
        const float2* a2 = (const float2*)amp;
        const float2* p2 = (const float2*)ph;
        float a0 = 0.f, a1 = 0.f, b0 = 0.f, b1 = 0.f;
#pragma unroll 4
        for (int t = 0; t < NS; ++t) {
            float2 av = a2[t * NP + p];
            float2 pv = p2[t * NP + p];
            float w = W_l[t], in = in_l[t];
            float ra0 = av.x * in * (__cosf(pv.x) + __sinf(pv.x));
            float ra1 = av.y * in * (__cosf(pv.y) + __sinf(pv.y));
            float wr0 = w * ra0, wr1 = w * ra1;
            a0 += wr0 * G_l[4 * t + 0];
            b0 += wr0 * G_l[4 * t + 2];
            a1 += wr1 * G_l[4 * t + 1];
            b1 += wr1 * G_l[4 * t + 3];
        }
        float2 m0v = {a0, a1}, m1v = {b0, b1};
        ((float2*)(M0 + srow * ND))[p] = m0v;
        ((float2*)(M1 + srow * ND))[p] = m1v;
        Qt[(3 * p + 0) * NS + srow] = a0 * a0 + a1 * a1;
        Qt[(3 * p + 1) * NS + srow] = a0 * b0 + a1 * b1;
        Qt[(3 * p + 2) * NS + srow] = b0 * b0 + b1 * b1;
    }
    grid_barrier(&bar[2], S + NBLK);

    // ---------------- phase 2: logits + collapse + output; 2 b-rows/block ----
    {
        const int r0 = 2 * blk;  // rows r0, r0+1
        // stage x rows into LDS (coalesced float4)
        const float4* x4 = (const float4*)(x + r0 * ND);  // 1024 float4s
        float4* xs4 = (float4*)xs;
#pragma unroll
        for (int i = 0; i < 4; ++i) xs4[tid + i * 256] = x4[tid + i * 256];
        __syncthreads();

        const int w = tid >> 6, s = tid & 63;
        const float2* xr0 = xs;
        const float2* xr1 = xs + NP;
        float acc0 = 0.f, acc1 = 0.f;
        const int p0 = w << 8;
#pragma unroll 4
        for (int p = p0; p < p0 + 256; ++p) {
            float q0 = Qt[(3 * p + 0) * NS + s];
            float q1 = Qt[(3 * p + 1) * NS + s];
            float q2 = Qt[(3 * p + 2) * NS + s];
            float2 v0 = xr0[p], v1 = xr1[p];
            acc0 += v0.x * v0.x * q0 + 2.f * v0.x * v0.y * q1 + v0.y * v0.y * q2;
            acc1 += v1.x * v1.x * q0 + 2.f * v1.x * v1.y * q1 + v1.y * v1.y * q2;
        }
        part[0][w][s] = acc0;
        part[1][w][s] = acc1;
        __syncthreads();

        if (w < 2) {  // wave r handles row r0+r: gumbel-max (exact jax categorical)
            float l = part[w][0][s] + part[w][1][s] + part[w][2][s] + part[w][3][s];
            unsigned n = (unsigned)((r0 + w) * NS + s);
            unsigned t0 = 0u, t1 = n;  // partitionable counter = (hi32(n), lo32(n))
            threefry2x32(0u, 42u, t0, t1);
            unsigned bits = t0 ^ t1;
            float u = (float)(bits >> 9) * (1.0f / 8388608.0f);
            u = fmaxf(u, 1.17549435e-38f);
            float g = -logf(-logf(u));
            float best = l + g;
            int bi = s;
            for (int off = 32; off; off >>= 1) {
                float ov = __shfl_down(best, off);
                int oi = __shfl_down(bi, off);
                if (ov > best || (ov == best && oi < bi)) { best = ov; bi = oi; }
            }
            if (s == 0) o_sh[w] = bi;
        }
        __syncthreads();

#pragma unroll
        for (int r = 0; r < 2; ++r) {
            const int o = o_sh[r];
            const float2* m0p = (const float2*)(M0 + o * ND);
            const float2* m1p = (const float2*)(M1 + o * ND);
            const float2* xr = xs + r * NP;
            float2* op = (float2*)(out + (r0 + r) * ND);
#pragma unroll
            for (int k = 0; k < 4; ++k) {
                int p = tid + (k << 8);
                float2 xv = xr[p], m0 = m0p[p], m1 = m1p[p];
                float2 rr;
                rr.x = xv.x * m0.x + xv.y * m1.x;
                rr.y = xv.x * m0.y + xv.y * m1.y;
                op[p] = rr;
            }
        }
    }

    // exit cleanup: last block restores counters to sentinel so a call without
    // re-poison still works (no one waits on bar[3]).
    if (tid == 0) {
        __threadfence();
        int old = atomicAdd(&bar[3], 1);
        if (old == S + NBLK - 1) {
            atomicExch(&bar[1], S);
            atomicExch(&bar[2], S);
            atomicExch(&bar[3], S);
        }
    }
}

extern "C" void kernel_launch(void* const* d_in, const int* in_sizes, int n_in,
                              void* d_out, int out_size, void* d_ws, size_t ws_size,
                              hipStream_t stream) {
    const float* x   = (const float*)d_in[0];  // [512,2048]
    const float* amp = (const float*)d_in[1];  // [64,2048]
    const float* ph  = (const float*)d_in[2];  // [64,2048]
    const float* G   = (const float*)d_in[3];  // [64,2,2]
    const float* E   = (const float*)d_in[4];  // [64,64]
    float* out = (float*)d_out;
    float* ws = (float*)d_ws;

    // ws layout (float offsets). bar[0] = sentinel (never written).
    int*   bar  = (int*)ws;            // 16 ints
    float* invn = ws + 16;             // 64
    float* Wm   = ws + 80;             // 4096
    float* M0   = ws + 4608;           // 131072
    float* M1   = ws + 135680;         // 131072
    float* Qt   = ws + 266752;         // 196608 (ends at 463360 floats ~ 1.85 MB)

    k_all<<<NBLK, 256, 0, stream>>>(x, amp, ph, G, E, out, bar, invn, Wm, M0, M1, Qt);
}

// Round 7
// 99.073 us; speedup vs baseline: 1.5151x; 1.4480x over previous
//
#include <hip/hip_runtime.h>
#include <math.h>

#define NB 512
#define NS 64
#define ND 2048
#define NP 1024   // ND/2

// ---------------- threefry2x32 (exact jax semantics, key=(0,42)) -------------
__device__ __forceinline__ unsigned rotl32(unsigned x, int d) {
    return (x << d) | (x >> (32 - d));
}

__device__ __forceinline__ void threefry2x32(unsigned k0, unsigned k1,
                                             unsigned& x0, unsigned& x1) {
    const unsigned ks0 = k0, ks1 = k1, ks2 = k0 ^ k1 ^ 0x1BD11BDAu;
    const int r0[4] = {13, 15, 26, 6};
    const int r1[4] = {17, 29, 16, 24};
    x0 += ks0; x1 += ks1;
#pragma unroll
    for (int i = 0; i < 4; ++i) { x0 += x1; x1 = rotl32(x1, r0[i]); x1 ^= x0; }
    x0 += ks1; x1 += ks2 + 1u;
#pragma unroll
    for (int i = 0; i < 4; ++i) { x0 += x1; x1 = rotl32(x1, r1[i]); x1 ^= x0; }
    x0 += ks2; x1 += ks0 + 2u;
#pragma unroll
    for (int i = 0; i < 4; ++i) { x0 += x1; x1 = rotl32(x1, r0[i]); x1 ^= x0; }
    x0 += ks0; x1 += ks1 + 3u;
#pragma unroll
    for (int i = 0; i < 4; ++i) { x0 += x1; x1 = rotl32(x1, r1[i]); x1 ^= x0; }
    x0 += ks1; x1 += ks2 + 4u;
#pragma unroll
    for (int i = 0; i < 4; ++i) { x0 += x1; x1 = rotl32(x1, r0[i]); x1 ^= x0; }
    x0 += ks2; x1 += ks0 + 5u;
}

// ---------------- K1: norms+softmax (redundant per block) + M0/M1/Qt ---------
// 256 blocks x 256 threads: s-row = blk>>2, pair chunk = (blk&3)*256.
__global__ void __launch_bounds__(256)
k_MQ(const float* __restrict__ amp, const float* __restrict__ ph,
     const float* __restrict__ G, const float* __restrict__ E,
     float* __restrict__ M0, float* __restrict__ M1, float* __restrict__ Qt) {
    __shared__ float norm2[NS];
    __shared__ float W_l[NS], in_l[NS];
    __shared__ float Gl[NS * 4];
    const int blk = blockIdx.x;
    const int tid = threadIdx.x;
    const int srow = blk >> 2;

    // redundant norms: 4 threads per amp row, float4 loads, stride-4 interleave
    {
        const int r = tid >> 2, sub = tid & 3;
        const float4* a4 = (const float4*)(amp + r * ND);  // 512 float4/row
        float acc = 0.f;
#pragma unroll 8
        for (int i = 0; i < 128; ++i) {
            float4 v = a4[sub + 4 * i];
            acc += v.x * v.x + v.y * v.y + v.z * v.z + v.w * v.w;
        }
        acc += __shfl_xor(acc, 1, 4);
        acc += __shfl_xor(acc, 2, 4);
        if (sub == 0) norm2[r] = acc;
    }
    Gl[tid] = G[tid];  // 256 = NS*4
    __syncthreads();
    if (tid < NS) {  // wave 0: inv-norm + softmax of this block's E row
        in_l[tid] = 1.0f / sqrtf(norm2[tid]);
        float e = E[srow * NS + tid];
        float m = e;
        for (int off = 32; off; off >>= 1) m = fmaxf(m, __shfl_down(m, off));
        m = __shfl(m, 0);
        float ex = expf(e - m);
        float sum = ex;
        for (int off = 32; off; off >>= 1) sum += __shfl_down(sum, off);
        sum = __shfl(sum, 0);
        W_l[tid] = ex / sum;
    }
    __syncthreads();

    // main: thread = pair p in [0,1024); M0/M1[srow, 2p..2p+1] and Qt[., srow]
    const int p = ((blk & 3) << 8) + tid;
    const float2* a2 = (const float2*)amp;
    const float2* p2 = (const float2*)ph;
    float a0 = 0.f, a1 = 0.f, b0 = 0.f, b1 = 0.f;
#pragma unroll 4
    for (int t = 0; t < NS; ++t) {
        float2 av = a2[t * NP + p];
        float2 pv = p2[t * NP + p];
        float w = W_l[t], in = in_l[t];
        float ra0 = av.x * in * (__cosf(pv.x) + __sinf(pv.x));
        float ra1 = av.y * in * (__cosf(pv.y) + __sinf(pv.y));
        float wr0 = w * ra0, wr1 = w * ra1;
        a0 += wr0 * Gl[4 * t + 0];
        b0 += wr0 * Gl[4 * t + 2];
        a1 += wr1 * Gl[4 * t + 1];
        b1 += wr1 * Gl[4 * t + 3];
    }
    float2 m0v = {a0, a1}, m1v = {b0, b1};
    ((float2*)(M0 + srow * ND))[p] = m0v;
    ((float2*)(M1 + srow * ND))[p] = m1v;
    Qt[(3 * p + 0) * NS + srow] = a0 * a0 + a1 * a1;
    Qt[(3 * p + 1) * NS + srow] = a0 * b0 + a1 * b1;
    Qt[(3 * p + 2) * NS + srow] = b0 * b0 + b1 * b1;
}

// ---------------- K2: per-row logits + collapse + output ---------------------
// 512 blocks x 512 threads (8 waves: K split 8 ways), 16 waves/CU.
__global__ void __launch_bounds__(512)
k_row(const float* __restrict__ x, const float* __restrict__ Qt,
      const float* __restrict__ M0, const float* __restrict__ M1,
      float* __restrict__ out) {
    __shared__ float2 xs[NP];        // 8 KB: this row of x, as pairs
    __shared__ float part[8][NS];    // 2 KB
    __shared__ int o_sh;
    const int b = blockIdx.x;
    const int tid = threadIdx.x;

    // stage x row (coalesced float4)
    ((float4*)xs)[tid] = ((const float4*)(x + b * ND))[tid];  // 512 float4
    __syncthreads();

    const int w = tid >> 6, s = tid & 63;
    {
        float acc = 0.f;
        const int p0 = w << 7;  // 128 pairs per wave
#pragma unroll 4
        for (int p = p0; p < p0 + 128; ++p) {
            float q0 = Qt[(3 * p + 0) * NS + s];
            float q1 = Qt[(3 * p + 1) * NS + s];
            float q2 = Qt[(3 * p + 2) * NS + s];
            float2 v = xs[p];
            acc += v.x * v.x * q0 + 2.f * v.x * v.y * q1 + v.y * v.y * q2;
        }
        part[w][s] = acc;
    }
    __syncthreads();

    if (tid < 64) {  // wave 0: exact jax categorical via gumbel-max
        float l = 0.f;
#pragma unroll
        for (int k = 0; k < 8; ++k) l += part[k][tid];
        unsigned n = (unsigned)(b * NS + tid);
        unsigned t0 = 0u, t1 = n;  // partitionable counter = (hi32(n), lo32(n))
        threefry2x32(0u, 42u, t0, t1);
        unsigned bits = t0 ^ t1;
        float u = (float)(bits >> 9) * (1.0f / 8388608.0f);
        u = fmaxf(u, 1.17549435e-38f);
        float g = -logf(-logf(u));
        float best = l + g;
        int bi = tid;
        for (int off = 32; off; off >>= 1) {
            float ov = __shfl_down(best, off);
            int oi = __shfl_down(bi, off);
            if (ov > best || (ov == best && oi < bi)) { best = ov; bi = oi; }
        }
        if (tid == 0) o_sh = bi;
    }
    __syncthreads();

    const int o = o_sh;
    const float2* m0p = (const float2*)(M0 + o * ND);
    const float2* m1p = (const float2*)(M1 + o * ND);
    float2* op = (float2*)(out + b * ND);
#pragma unroll
    for (int k = 0; k < 2; ++k) {
        int p = tid + (k << 9);
        float2 xv = xs[p], m0 = m0p[p], m1 = m1p[p];
        float2 r;
        r.x = xv.x * m0.x + xv.y * m1.x;
        r.y = xv.x * m0.y + xv.y * m1.y;
        op[p] = r;
    }
}

extern "C" void kernel_launch(void* const* d_in, const int* in_sizes, int n_in,
                              void* d_out, int out_size, void* d_ws, size_t ws_size,
                              hipStream_t stream) {
    const float* x   = (const float*)d_in[0];  // [512,2048]
    const float* amp = (const float*)d_in[1];  // [64,2048]
    const float* ph  = (const float*)d_in[2];  // [64,2048]
    const float* G   = (const float*)d_in[3];  // [64,2,2]
    const float* E   = (const float*)d_in[4];  // [64,64]
    float* out = (float*)d_out;
    float* ws = (float*)d_ws;

    // ws layout (float offsets)
    float* M0 = ws;             // 131072
    float* M1 = ws + 131072;    // 131072
    float* Qt = ws + 262144;    // 196608 (ends ~1.83 MB)

    k_MQ <<<256, 256, 0, stream>>>(amp, ph, G, E, M0, M1, Qt);
    k_row<<<512, 512, 0, stream>>>(x, Qt, M0, M1, out);
}

// Round 8
// 90.577 us; speedup vs baseline: 1.6572x; 1.0938x over previous
//
#include <hip/hip_runtime.h>
#include <math.h>

#define NB 512
#define NS 64
#define ND 2048
#define NP 1024   // ND/2

// ---------------- threefry2x32 (exact jax semantics, key=(0,42)) -------------
__device__ __forceinline__ unsigned rotl32(unsigned x, int d) {
    return (x << d) | (x >> (32 - d));
}

__device__ __forceinline__ void threefry2x32(unsigned k0, unsigned k1,
                                             unsigned& x0, unsigned& x1) {
    const unsigned ks0 = k0, ks1 = k1, ks2 = k0 ^ k1 ^ 0x1BD11BDAu;
    const int r0[4] = {13, 15, 26, 6};
    const int r1[4] = {17, 29, 16, 24};
    x0 += ks0; x1 += ks1;
#pragma unroll
    for (int i = 0; i < 4; ++i) { x0 += x1; x1 = rotl32(x1, r0[i]); x1 ^= x0; }
    x0 += ks1; x1 += ks2 + 1u;
#pragma unroll
    for (int i = 0; i < 4; ++i) { x0 += x1; x1 = rotl32(x1, r1[i]); x1 ^= x0; }
    x0 += ks2; x1 += ks0 + 2u;
#pragma unroll
    for (int i = 0; i < 4; ++i) { x0 += x1; x1 = rotl32(x1, r0[i]); x1 ^= x0; }
    x0 += ks0; x1 += ks1 + 3u;
#pragma unroll
    for (int i = 0; i < 4; ++i) { x0 += x1; x1 = rotl32(x1, r1[i]); x1 ^= x0; }
    x0 += ks1; x1 += ks2 + 4u;
#pragma unroll
    for (int i = 0; i < 4; ++i) { x0 += x1; x1 = rotl32(x1, r0[i]); x1 ^= x0; }
    x0 += ks2; x1 += ks0 + 5u;
}

// ---------------- K1: norms+softmax (redundant per block) + M0/M1/Qt ---------
// 256 blocks x 1024 threads: s-row = blk>>2, pair chunk = (blk&3)*256.
// t-loop split 4x across wave-groups (16 t each) -> 4 waves/SIMD.
__global__ void __launch_bounds__(1024)
k_MQ(const float* __restrict__ amp, const float* __restrict__ ph,
     const float* __restrict__ G, const float* __restrict__ E,
     float* __restrict__ M0, float* __restrict__ M1, float* __restrict__ Qt) {
    __shared__ float norm2[NS];
    __shared__ float W_l[NS], in_l[NS];
    __shared__ float Gl[NS * 4];
    __shared__ float4 part4[4][256];   // 16 KB: per-tgroup partial (a0,a1,b0,b1)
    const int blk = blockIdx.x;
    const int tid = threadIdx.x;
    const int srow = blk >> 2;

    // redundant norms: 16 threads per amp row, float4 loads, stride-16 interleave
    {
        const int r = tid >> 4, sub = tid & 15;
        const float4* a4 = (const float4*)(amp + r * ND);  // 512 float4/row
        float acc = 0.f;
#pragma unroll 8
        for (int i = 0; i < 32; ++i) {
            float4 v = a4[sub + 16 * i];
            acc += v.x * v.x + v.y * v.y + v.z * v.z + v.w * v.w;
        }
        acc += __shfl_down(acc, 8, 16);
        acc += __shfl_down(acc, 4, 16);
        acc += __shfl_down(acc, 2, 16);
        acc += __shfl_down(acc, 1, 16);
        if (sub == 0) norm2[r] = acc;
    }
    if (tid < NS * 4) Gl[tid] = G[tid];
    __syncthreads();
    if (tid < NS) {  // wave 0: inv-norm + softmax of this block's E row
        in_l[tid] = 1.0f / sqrtf(norm2[tid]);
        float e = E[srow * NS + tid];
        float m = e;
        for (int off = 32; off; off >>= 1) m = fmaxf(m, __shfl_down(m, off));
        m = __shfl(m, 0);
        float ex = expf(e - m);
        float sum = ex;
        for (int off = 32; off; off >>= 1) sum += __shfl_down(sum, off);
        sum = __shfl(sum, 0);
        W_l[tid] = ex / sum;
    }
    __syncthreads();

    // main: thread = (pair pi, t-group); 16 t's each, partials to LDS
    {
        const int pi = tid & 255;
        const int tg = tid >> 8;           // 0..3
        const int p = ((blk & 3) << 8) + pi;
        const int t0 = tg << 4;
        const float2* a2 = (const float2*)amp;
        const float2* p2 = (const float2*)ph;
        float a0 = 0.f, a1 = 0.f, b0 = 0.f, b1 = 0.f;
#pragma unroll 4
        for (int t = t0; t < t0 + 16; ++t) {
            float2 av = a2[t * NP + p];
            float2 pv = p2[t * NP + p];
            float w = W_l[t], in = in_l[t];
            float ra0 = av.x * in * (__cosf(pv.x) + __sinf(pv.x));
            float ra1 = av.y * in * (__cosf(pv.y) + __sinf(pv.y));
            float wr0 = w * ra0, wr1 = w * ra1;
            a0 += wr0 * Gl[4 * t + 0];
            b0 += wr0 * Gl[4 * t + 2];
            a1 += wr1 * Gl[4 * t + 1];
            b1 += wr1 * Gl[4 * t + 3];
        }
        part4[tg][pi] = make_float4(a0, a1, b0, b1);
    }
    __syncthreads();

    if (tid < 256) {  // combine 4 partials, write M0/M1/Qt
        const int p = ((blk & 3) << 8) + tid;
        float4 s0 = part4[0][tid], s1 = part4[1][tid],
               s2 = part4[2][tid], s3 = part4[3][tid];
        float a0 = s0.x + s1.x + s2.x + s3.x;
        float a1 = s0.y + s1.y + s2.y + s3.y;
        float b0 = s0.z + s1.z + s2.z + s3.z;
        float b1 = s0.w + s1.w + s2.w + s3.w;
        float2 m0v = {a0, a1}, m1v = {b0, b1};
        ((float2*)(M0 + srow * ND))[p] = m0v;
        ((float2*)(M1 + srow * ND))[p] = m1v;
        Qt[(3 * p + 0) * NS + srow] = a0 * a0 + a1 * a1;
        Qt[(3 * p + 1) * NS + srow] = a0 * b0 + a1 * b1;
        Qt[(3 * p + 2) * NS + srow] = b0 * b0 + b1 * b1;
    }
}

// ---------------- K2: logits + collapse + output; 2 rows/block ---------------
// 256 blocks x 1024 threads (16 waves, 4/SIMD): wave w = p-chunk [64w,64w+64),
// both rows. Halves aggregate Qt L2 traffic vs 1 row/block.
__global__ void __launch_bounds__(1024)
k_row(const float* __restrict__ x, const float* __restrict__ Qt,
      const float* __restrict__ M0, const float* __restrict__ M1,
      float* __restrict__ out) {
    __shared__ float2 xs[2 * NP];      // 16 KB: two x rows, as pairs
    __shared__ float part[16][2][NS];  // 8 KB
    __shared__ int o_sh[2];
    const int blk = blockIdx.x;
    const int tid = threadIdx.x;
    const int r0 = 2 * blk;

    // stage 2 x rows (coalesced float4: 1024 of them)
    ((float4*)xs)[tid] = ((const float4*)(x + r0 * ND))[tid];
    __syncthreads();

    const int w = tid >> 6, s = tid & 63;
    {
        float acc0 = 0.f, acc1 = 0.f;
        const int p0 = w << 6;  // 64 pairs per wave
#pragma unroll 4
        for (int p = p0; p < p0 + 64; ++p) {
            float q0 = Qt[(3 * p + 0) * NS + s];
            float q1 = Qt[(3 * p + 1) * NS + s];
            float q2 = Qt[(3 * p + 2) * NS + s];
            float2 v0 = xs[p], v1 = xs[NP + p];
            acc0 += v0.x * v0.x * q0 + 2.f * v0.x * v0.y * q1 + v0.y * v0.y * q2;
            acc1 += v1.x * v1.x * q0 + 2.f * v1.x * v1.y * q1 + v1.y * v1.y * q2;
        }
        part[w][0][s] = acc0;
        part[w][1][s] = acc1;
    }
    __syncthreads();

    if (tid < 128) {  // waves 0-1: row r = w2; exact jax categorical (gumbel-max)
        const int w2 = tid >> 6;
        float l = 0.f;
#pragma unroll
        for (int k = 0; k < 16; ++k) l += part[k][w2][s];
        unsigned n = (unsigned)((r0 + w2) * NS + s);
        unsigned t0 = 0u, t1 = n;  // partitionable counter = (hi32(n), lo32(n))
        threefry2x32(0u, 42u, t0, t1);
        unsigned bits = t0 ^ t1;
        float u = (float)(bits >> 9) * (1.0f / 8388608.0f);
        u = fmaxf(u, 1.17549435e-38f);
        float g = -logf(-logf(u));
        float best = l + g;
        int bi = s;
        for (int off = 32; off; off >>= 1) {
            float ov = __shfl_down(best, off);
            int oi = __shfl_down(bi, off);
            if (ov > best || (ov == best && oi < bi)) { best = ov; bi = oi; }
        }
        if (s == 0) o_sh[w2] = bi;
    }
    __syncthreads();

#pragma unroll
    for (int r = 0; r < 2; ++r) {
        const int o = o_sh[r];
        const float2* m0p = (const float2*)(M0 + o * ND);
        const float2* m1p = (const float2*)(M1 + o * ND);
        const float2* xr = xs + r * NP;
        float2* op = (float2*)(out + (r0 + r) * ND);
        float2 xv = xr[tid], m0 = m0p[tid], m1 = m1p[tid];
        float2 rr;
        rr.x = xv.x * m0.x + xv.y * m1.x;
        rr.y = xv.x * m0.y + xv.y * m1.y;
        op[tid] = rr;
    }
}

extern "C" void kernel_launch(void* const* d_in, const int* in_sizes, int n_in,
                              void* d_out, int out_size, void* d_ws, size_t ws_size,
                              hipStream_t stream) {
    const float* x   = (const float*)d_in[0];  // [512,2048]
    const float* amp = (const float*)d_in[1];  // [64,2048]
    const float* ph  = (const float*)d_in[2];  // [64,2048]
    const float* G   = (const float*)d_in[3];  // [64,2,2]
    const float* E   = (const float*)d_in[4];  // [64,64]
    float* out = (float*)d_out;
    float* ws = (float*)d_ws;

    // ws layout (float offsets)
    float* M0 = ws;             // 131072
    float* M1 = ws + 131072;    // 131072
    float* Qt = ws + 262144;    // 196608 (ends ~1.83 MB)

    k_MQ <<<256, 1024, 0, stream>>>(amp, ph, G, E, M0, M1, Qt);
    k_row<<<256, 1024, 0, stream>>>(x, Qt, M0, M1, out);
}